// Round 1
// baseline (380.718 us; speedup 1.0000x reference)
//
#include <hip/hip_runtime.h>

#define NUM_IMG 65536
#define IMG_PIX 784     // 28*28
#define NCLS 10

__global__ __launch_bounds__(256) void quanv_logits_kernel(
    const float* __restrict__ x,    // (B,1,28,28)
    const float* __restrict__ W,    // (10, 784)
    const float* __restrict__ bias, // (10,)
    float* __restrict__ out)        // (B, 10)
{
    const int img = blockIdx.x * blockDim.x + threadIdx.x;
    const float* __restrict__ p = x + (size_t)img * IMG_PIX;

    float acc[NCLS];
#pragma unroll
    for (int c = 0; c < NCLS; ++c) acc[c] = bias[c];

    // Iterate over 14 patch-rows; each consumes two 28-float image rows.
    for (int i = 0; i < 14; ++i) {
        float rowt[28], rowb[28];
        const float4* rt = reinterpret_cast<const float4*>(p + i * 56);
        const float4* rb = reinterpret_cast<const float4*>(p + i * 56 + 28);
#pragma unroll
        for (int q = 0; q < 7; ++q) {
            float4 t = rt[q];
            float4 bm = rb[q];
            rowt[4*q+0] = t.x;  rowt[4*q+1] = t.y;  rowt[4*q+2] = t.z;  rowt[4*q+3] = t.w;
            rowb[4*q+0] = bm.x; rowb[4*q+1] = bm.y; rowb[4*q+2] = bm.z; rowb[4*q+3] = bm.w;
        }
        const int rowbase = i * 14;
#pragma unroll
        for (int j = 0; j < 14; ++j) {
            // patch (i,j): pixels (2i,2j),(2i,2j+1),(2i+1,2j),(2i+1,2j+1)
            float e0 = __cosf(rowt[2*j]);
            float e1 = e0 * __cosf(rowt[2*j + 1]);
            float e2 = e1 * __cosf(rowb[2*j]);
            float e3 = e2 * __cosf(rowb[2*j + 1]);
            const int base = (rowbase + j) * 4;   // wave-uniform
#pragma unroll
            for (int c = 0; c < NCLS; ++c) {
                float4 w = *reinterpret_cast<const float4*>(W + c * IMG_PIX + base);
                acc[c] = fmaf(e0, w.x, acc[c]);
                acc[c] = fmaf(e1, w.y, acc[c]);
                acc[c] = fmaf(e2, w.z, acc[c]);
                acc[c] = fmaf(e3, w.w, acc[c]);
            }
        }
    }

    // log_softmax over the 10 logits
    float m = acc[0];
#pragma unroll
    for (int c = 1; c < NCLS; ++c) m = fmaxf(m, acc[c]);
    float s = 0.0f;
#pragma unroll
    for (int c = 0; c < NCLS; ++c) s += __expf(acc[c] - m);
    const float lse = __logf(s) + m;

    float* o = out + (size_t)img * NCLS;
    float2 v;
#pragma unroll
    for (int c = 0; c < NCLS; c += 2) {
        v.x = acc[c] - lse;
        v.y = acc[c + 1] - lse;
        *reinterpret_cast<float2*>(o + c) = v;
    }
}

extern "C" void kernel_launch(void* const* d_in, const int* in_sizes, int n_in,
                              void* d_out, int out_size, void* d_ws, size_t ws_size,
                              hipStream_t stream) {
    const float* x    = (const float*)d_in[0];
    const float* W    = (const float*)d_in[1];
    const float* bias = (const float*)d_in[2];
    float* out        = (float*)d_out;

    dim3 block(256);
    dim3 grid(NUM_IMG / 256);
    quanv_logits_kernel<<<grid, block, 0, stream>>>(x, W, bias, out);
}

// Round 2
// 320.054 us; speedup vs baseline: 1.1895x; 1.1895x over previous
//
#include <hip/hip_runtime.h>

#define NCLS 10
#define IMG_PIX 784     // 28*28
#define NUM_IMG 65536

// Block = 448 threads = 7 waves, covering 64 images.
// Wave w handles patch-rows {w, w+7} for all 64 images (lane = image).
// Row index is wave-uniform (readfirstlane) so W loads stay scalar
// (s_load_dwordx4) -> W read once per wave, not per lane.
__global__ __launch_bounds__(448, 7) void quanv_logits_kernel(
    const float* __restrict__ x,    // (B,1,28,28)
    const float* __restrict__ W,    // (10, 784)
    const float* __restrict__ bias, // (10,)
    float* __restrict__ out)        // (B, 10)
{
    // [64 images][73] floats; stride 73 = 9 mod 32 -> conflict-free (2-way)
    __shared__ float part[64][73];

    const int tid  = threadIdx.x;
    const int wv   = __builtin_amdgcn_readfirstlane(tid >> 6); // 0..6, uniform
    const int lane = tid & 63;                                  // image in block
    const int img  = (blockIdx.x << 6) + lane;
    const float* __restrict__ p = x + (size_t)img * IMG_PIX;

    float acc[NCLS];
#pragma unroll
    for (int c = 0; c < NCLS; ++c) acc[c] = 0.0f;

#pragma unroll
    for (int rr = 0; rr < 2; ++rr) {
        const int r = wv + rr * 7;   // patch-row, uniform across the wave
        float rowt[28], rowb[28];
        const float4* rt = reinterpret_cast<const float4*>(p + r * 56);
        const float4* rb = reinterpret_cast<const float4*>(p + r * 56 + 28);
#pragma unroll
        for (int q = 0; q < 7; ++q) {
            float4 t  = rt[q];
            float4 bm = rb[q];
            rowt[4*q+0] = t.x;  rowt[4*q+1] = t.y;  rowt[4*q+2] = t.z;  rowt[4*q+3] = t.w;
            rowb[4*q+0] = bm.x; rowb[4*q+1] = bm.y; rowb[4*q+2] = bm.z; rowb[4*q+3] = bm.w;
        }
        const int rowbase = r * 14;  // uniform
#pragma unroll
        for (int j = 0; j < 14; ++j) {
            float e0 = __cosf(rowt[2*j]);
            float e1 = e0 * __cosf(rowt[2*j + 1]);
            float e2 = e1 * __cosf(rowb[2*j]);
            float e3 = e2 * __cosf(rowb[2*j + 1]);
            const int base = (rowbase + j) * 4;   // uniform -> scalar W loads
#pragma unroll
            for (int c = 0; c < NCLS; ++c) {
                float4 wq = *reinterpret_cast<const float4*>(W + c * IMG_PIX + base);
                acc[c] = fmaf(e0, wq.x, acc[c]);
                acc[c] = fmaf(e1, wq.y, acc[c]);
                acc[c] = fmaf(e2, wq.z, acc[c]);
                acc[c] = fmaf(e3, wq.w, acc[c]);
            }
        }
    }

    // Deposit partial logits
#pragma unroll
    for (int c = 0; c < NCLS; ++c) part[lane][wv * NCLS + c] = acc[c];
    __syncthreads();

    // Wave 0: reduce across the 7 waves, bias, log-softmax, store
    if (wv == 0) {
        float s[NCLS];
#pragma unroll
        for (int c = 0; c < NCLS; ++c) s[c] = bias[c];
        for (int ww = 0; ww < 7; ++ww) {
#pragma unroll
            for (int c = 0; c < NCLS; ++c) s[c] += part[lane][ww * NCLS + c];
        }
        float m = s[0];
#pragma unroll
        for (int c = 1; c < NCLS; ++c) m = fmaxf(m, s[c]);
        float sum = 0.0f;
#pragma unroll
        for (int c = 0; c < NCLS; ++c) sum += __expf(s[c] - m);
        const float lse = __logf(sum) + m;

        float* o = out + (size_t)img * NCLS;
#pragma unroll
        for (int c = 0; c < NCLS; c += 2) {
            float2 v;
            v.x = s[c]     - lse;
            v.y = s[c + 1] - lse;
            *reinterpret_cast<float2*>(o + c) = v;
        }
    }
}

extern "C" void kernel_launch(void* const* d_in, const int* in_sizes, int n_in,
                              void* d_out, int out_size, void* d_ws, size_t ws_size,
                              hipStream_t stream) {
    const float* x    = (const float*)d_in[0];
    const float* W    = (const float*)d_in[1];
    const float* bias = (const float*)d_in[2];
    float* out        = (float*)d_out;

    dim3 block(448);               // 7 waves
    dim3 grid(NUM_IMG / 64);       // 1024 blocks, 64 images each
    quanv_logits_kernel<<<grid, block, 0, stream>>>(x, W, bias, out);
}

// Round 3
// 303.291 us; speedup vs baseline: 1.2553x; 1.0553x over previous
//
#include <hip/hip_runtime.h>

#define NCLS 10
#define NUM_IMG 65536

// Async global->LDS, 16B per lane. LDS dest = wave-uniform base + lane*16.
__device__ __forceinline__ void async_cp16(const float* g, float* l) {
    __builtin_amdgcn_global_load_lds(
        (const __attribute__((address_space(1))) void*)(g),
        (__attribute__((address_space(3))) void*)(l),
        16, 0, 0);
}

// Block = 448 threads (7 waves) over 64 images (lane = image).
// Image row-pair rr occupies bytes [224*rr, 224*rr+224) = f4 indices k=0..13
// (k=0..6 top row, k=7..13 bottom row). Staged into LDS as [k][img] float4
// via global_load_lds (wave w stages k=2w,2w+1), double-buffered across rr.
// Wave w computes patch-columns j=2w,2w+1 (top pair = f4[w].xy/.zw, bottom
// pair = f4[w+7].xy/.zw), so W indices are wave-uniform -> scalar s_loads.
__global__ __launch_bounds__(448, 7) void quanv_logits_kernel(
    const float* __restrict__ x,    // (B,1,28,28)
    const float* __restrict__ W,    // (10, 784)
    const float* __restrict__ bias, // (10,)
    float* __restrict__ out)        // (B, 10)
{
    __shared__ float sb[2 * 14 * 256];   // 2 x 14-KB row-pair buffers (28672 B)

    const int tid  = threadIdx.x;
    const int w    = __builtin_amdgcn_readfirstlane(tid >> 6); // 0..6 uniform
    const int lane = tid & 63;                                  // image in block
    const int img0 = blockIdx.x << 6;
    const float* __restrict__ xg = x + (size_t)(img0 + lane) * 784;

    float acc[NCLS];
#pragma unroll
    for (int c = 0; c < NCLS; ++c) acc[c] = 0.0f;

    const int k0 = 2 * w, k1 = 2 * w + 1;

    // Prologue: stage rr=0 into buffer 0
    async_cp16(xg + k0 * 4, &sb[k0 * 256]);
    async_cp16(xg + k1 * 4, &sb[k1 * 256]);
    __syncthreads();   // drains vmcnt in every wave -> buffer 0 complete

#pragma unroll
    for (int rr = 0; rr < 14; ++rr) {
        const int cur = rr & 1, nxt = cur ^ 1;
        if (rr < 13) {  // prefetch next row-pair (fire-and-forget)
            const float* g = xg + (rr + 1) * 56;
            async_cp16(g + k0 * 4, &sb[(nxt * 14 + k0) * 256]);
            async_cp16(g + k1 * 4, &sb[(nxt * 14 + k1) * 256]);
        }

        // conflict-free ds_read_b128: addr = k*1024 + lane*16
        const float4 t4 = *reinterpret_cast<const float4*>(&sb[(cur * 14 + w) * 256 + lane * 4]);
        const float4 b4 = *reinterpret_cast<const float4*>(&sb[(cur * 14 + w + 7) * 256 + lane * 4]);

        // patch j=2w: cumprod(cos) over (tl, tr, bl, br)
        const float e0 = __cosf(t4.x);
        const float e1 = e0 * __cosf(t4.y);
        const float e2 = e1 * __cosf(b4.x);
        const float e3 = e2 * __cosf(b4.y);
        // patch j=2w+1
        const float f0 = __cosf(t4.z);
        const float f1 = f0 * __cosf(t4.w);
        const float f2 = f1 * __cosf(b4.z);
        const float f3 = f2 * __cosf(b4.w);

        const int P = (rr * 14 + 2 * w) * 4;  // uniform -> scalar W loads
#pragma unroll
        for (int c = 0; c < NCLS; ++c) {
            const float4 wa = *reinterpret_cast<const float4*>(&W[c * 784 + P]);
            const float4 wb = *reinterpret_cast<const float4*>(&W[c * 784 + P + 4]);
            float a = acc[c];
            a = fmaf(e0, wa.x, a); a = fmaf(e1, wa.y, a);
            a = fmaf(e2, wa.z, a); a = fmaf(e3, wa.w, a);
            a = fmaf(f0, wb.x, a); a = fmaf(f1, wb.y, a);
            a = fmaf(f2, wb.z, a); a = fmaf(f3, wb.w, a);
            acc[c] = a;
        }
        // Trailing barrier: (a) all reads of buf[cur] done before it is
        // restaged next iter; (b) each wave drained its own vmcnt, so after
        // the barrier buf[nxt] is fully staged for everyone.
        __syncthreads();
    }

    // Reduce the 7 per-wave partials. Reuse sb; stride 71 (odd) words.
    float* part = sb;
#pragma unroll
    for (int c = 0; c < NCLS; ++c) part[lane * 71 + w * NCLS + c] = acc[c];
    __syncthreads();

    if (w == 0) {
        float s[NCLS];
#pragma unroll
        for (int c = 0; c < NCLS; ++c) s[c] = bias[c];
        for (int ww = 0; ww < 7; ++ww) {
#pragma unroll
            for (int c = 0; c < NCLS; ++c) s[c] += part[lane * 71 + ww * NCLS + c];
        }
        float m = s[0];
#pragma unroll
        for (int c = 1; c < NCLS; ++c) m = fmaxf(m, s[c]);
        float sum = 0.0f;
#pragma unroll
        for (int c = 0; c < NCLS; ++c) sum += __expf(s[c] - m);
        const float lse = __logf(sum) + m;

        float* o = out + (size_t)(img0 + lane) * NCLS;
#pragma unroll
        for (int c = 0; c < NCLS; c += 2) {
            float2 v;
            v.x = s[c]     - lse;
            v.y = s[c + 1] - lse;
            *reinterpret_cast<float2*>(o + c) = v;
        }
    }
}

extern "C" void kernel_launch(void* const* d_in, const int* in_sizes, int n_in,
                              void* d_out, int out_size, void* d_ws, size_t ws_size,
                              hipStream_t stream) {
    const float* x    = (const float*)d_in[0];
    const float* W    = (const float*)d_in[1];
    const float* bias = (const float*)d_in[2];
    float* out        = (float*)d_out;

    dim3 block(448);               // 7 waves
    dim3 grid(NUM_IMG / 64);       // 1024 blocks, 64 images each
    quanv_logits_kernel<<<grid, block, 0, stream>>>(x, W, bias, out);
}